// Round 13
// baseline (32.576 us; speedup 1.0000x reference)
//
#include <hip/hip_runtime.h>

// PBC nonlinear compensation, D-factorized, single-conv-phase, R=2 + b128,
// packed-FP32 conv + parity-split E + C-via-VMEM + LDS-balanced groups:
//   O[b,k,i] = E[b,k,i] + sum_m sm(k;m) * E[b,k-m,i]        (Re part stored)
//   sm(k;m)  = sum_n C[m,n] * D_m[k-n]
//   D_m[x]   = sum_j E_j[x] * conj(E_j[x-m]),  D_{-m}[x] = conj(D_m[x+m])
//
// C is indexed through an opaque VGPR zero so loads emit global_load (vmcnt)
// instead of s_load (SMEM shares lgkmcnt with DS and returns out-of-order ->
// compiler drains lgkmcnt(0) at each use, killing ds_read pipelining).
// m-groups rebalanced by LDS instruction count (max 126 -> 88 per thread).

typedef float v2f __attribute__((ext_vector_type(2)));
typedef float v4f __attribute__((ext_vector_type(4)));

#define S_LEN 16384
#define SOUT  16284          // S - 2*L
#define BLK   512
#define NOUT  256            // outputs per block
#define NE    356            // staged E samples: [k0, k0+355]
#define NE2   178            // NE/2 (parity-split halves)
#define ND    307            // D tile: x in [k0+25, k0+331]
#define ND_AL 308            // row stride (pair-writable, 16B-aligned rows)
#define NDP   154            // ND_AL/2 pairs per row

constexpr int LIMS[26] = {25,25,12,8,6,5,4,3,3,2,2,2,2,
                          1,1,1,1,1,1,1,1,1,1,1,1,1};
constexpr int TS[51] = {
      0,  3,  6,  9, 12, 15, 18, 21, 24, 27, 30, 33, 36,
     39, 44, 49, 54, 59, 66, 73, 82, 93,106,123,148,199,
    250,301,326,343,356,367,376,383,390,395,400,405,410,
    413,416,419,422,425,428,431,434,437,440,443,446};

template<int M>
__device__ __forceinline__ void convM(
    const float2* __restrict__ sDm, const v4f* __restrict__ sEp,
    int o0, const float* __restrict__ Cr0, const float* __restrict__ Ci0,
    float4& acc)
{
    constexpr int lim = LIMS[M];
    constexpr int tp  = TS[25 + M];
    constexpr int tn  = TS[25 - M];
    constexpr int A   = 25 + lim;

    // packed accumulators: S{x,y}{P,N}{out0,out1}
    v2f SxP0 = {0.f,0.f}, SyP0 = {0.f,0.f}, SxP1 = {0.f,0.f}, SyP1 = {0.f,0.f};
    v2f SxN0 = {0.f,0.f}, SyN0 = {0.f,0.f}, SxN1 = {0.f,0.f}, SyN1 = {0.f,0.f};

#define TAP(dconst, dd)                                                     \
    {                                                                       \
        const int d_ = (dconst);                                            \
        if (A - d_ >= 0 && A - d_ <= 2*lim) {                               \
            const float cx = Cr0[tp + A - d_], cy = Ci0[tp + A - d_];       \
            SxP0 += cx * (dd);  SyP0 += cy * (dd);                          \
        }                                                                   \
        if (A + 1 - d_ >= 0 && A + 1 - d_ <= 2*lim) {                       \
            const float cx = Cr0[tp + A+1-d_], cy = Ci0[tp + A+1-d_];       \
            SxP1 += cx * (dd);  SyP1 += cy * (dd);                          \
        }                                                                   \
        if (A + M - d_ >= 0 && A + M - d_ <= 2*lim) {                       \
            const float cx = Cr0[tn + A+M-d_], cy = Ci0[tn + A+M-d_];       \
            SxN0 += cx * (dd);  SyN0 += cy * (dd);                          \
        }                                                                   \
        if (A + M + 1 - d_ >= 0 && A + M + 1 - d_ <= 2*lim) {               \
            const float cx = Cr0[tn + A+M+1-d_], cy = Ci0[tn + A+M+1-d_];   \
            SxN1 += cx * (dd);  SyN1 += cy * (dd);                          \
        }                                                                   \
    }

    if constexpr (M < 2*lim + 4) {
        // merged window: d in [25-lim, 26+lim+M]
        constexpr int dlo = (25 - lim) & ~1;
        constexpr int dhi = 26 + lim + M;
        constexpr int NP  = (dhi - dlo) / 2 + 1;
        #pragma unroll
        for (int p = 0; p < NP; ++p) {
            const int d0 = dlo + 2*p;
            v4f w = *reinterpret_cast<const v4f*>(&sDm[o0 + d0]);
            TAP(d0,     w.xy)
            TAP(d0 + 1, w.zw)
        }
    } else {
        // +m window: d in [25-lim, 26+lim]
        {
            constexpr int dlo = (25 - lim) & ~1;
            constexpr int dhi = 26 + lim;
            constexpr int NP  = (dhi - dlo) / 2 + 1;
            #pragma unroll
            for (int p = 0; p < NP; ++p) {
                const int d0 = dlo + 2*p;
                v4f w = *reinterpret_cast<const v4f*>(&sDm[o0 + d0]);
                #pragma unroll
                for (int e = 0; e < 2; ++e) {
                    const int d = d0 + e;
                    const v2f dd = e ? w.zw : w.xy;
                    if (A - d >= 0 && A - d <= 2*lim) {
                        const float cx = Cr0[tp + A - d], cy = Ci0[tp + A - d];
                        SxP0 += cx * dd;  SyP0 += cy * dd;
                    }
                    if (A + 1 - d >= 0 && A + 1 - d <= 2*lim) {
                        const float cx = Cr0[tp + A+1-d], cy = Ci0[tp + A+1-d];
                        SxP1 += cx * dd;  SyP1 += cy * dd;
                    }
                }
            }
        }
        // -m window: d in [25+M-lim, 26+M+lim]
        {
            constexpr int dlo = (25 + M - lim) & ~1;
            constexpr int dhi = 26 + M + lim;
            constexpr int NP  = (dhi - dlo) / 2 + 1;
            #pragma unroll
            for (int p = 0; p < NP; ++p) {
                const int d0 = dlo + 2*p;
                v4f w = *reinterpret_cast<const v4f*>(&sDm[o0 + d0]);
                #pragma unroll
                for (int e = 0; e < 2; ++e) {
                    const int d = d0 + e;
                    const v2f dd = e ? w.zw : w.xy;
                    if (A + M - d >= 0 && A + M - d <= 2*lim) {
                        const float cx = Cr0[tn + A+M-d], cy = Ci0[tn + A+M-d];
                        SxN0 += cx * dd;  SyN0 += cy * dd;
                    }
                    if (A + M + 1 - d >= 0 && A + M + 1 - d <= 2*lim) {
                        const float cx = Cr0[tn + A+M+1-d], cy = Ci0[tn + A+M+1-d];
                        SxN1 += cx * dd;  SyN1 += cy * dd;
                    }
                }
            }
        }
    }
#undef TAP

    // sign combination (deferred): +m: sr=Sx.x-Sy.y, si=Sx.y+Sy.x
    //                              -m (conj D): sr=Sx.x+Sy.y, si=Sy.x-Sx.y
    const float s0pr = SxP0.x - SyP0.y, s0pi = SxP0.y + SyP0.x;
    const float s1pr = SxP1.x - SyP1.y, s1pi = SxP1.y + SyP1.x;
    const float s0nr = SxN0.x + SyN0.y, s0ni = SyN0.x - SxN0.y;
    const float s1nr = SxN1.x + SyN1.y, s1ni = SyN1.x - SxN1.y;

    // parity-split E reads: all are sEp[t + const] (contiguous, aligned)
    const int t = o0 >> 1;
    v4f ep0, ep1, en0, en1;
    if constexpr ((M & 1) == 0) {
        ep0 = sEp[t + (50 - M)/2];          // even sample o0+50-M
        ep1 = sEp[t + (50 - M)/2 + NE2];    // odd  sample o0+51-M
        en0 = sEp[t + (50 + M)/2];
        en1 = sEp[t + (50 + M)/2 + NE2];
    } else {
        ep0 = sEp[t + (49 - M)/2 + NE2];    // odd  sample o0+50-M
        ep1 = sEp[t + (51 - M)/2];          // even sample o0+51-M
        en0 = sEp[t + (49 + M)/2 + NE2];
        en1 = sEp[t + (51 + M)/2];
    }
    acc.x += s0pr*ep0.x - s0pi*ep0.y + s0nr*en0.x - s0ni*en0.y;
    acc.y += s0pr*ep0.z - s0pi*ep0.w + s0nr*en0.z - s0ni*en0.w;
    acc.z += s1pr*ep1.x - s1pi*ep1.y + s1nr*en1.x - s1ni*en1.y;
    acc.w += s1pr*ep1.z - s1pi*ep1.w + s1nr*en1.z - s1ni*en1.w;
}

// m = 0: D real, taps j=0..50, c = C[199+j]; out0: j = 50-d, out1: j = 51-d.
__device__ __forceinline__ void conv0(
    const float* __restrict__ sD0p, const v4f* __restrict__ sEp,
    int o0, const float* __restrict__ Cr0, const float* __restrict__ Ci0,
    float4& acc)
{
    v2f s0 = {0.f, 0.f}, s1 = {0.f, 0.f};   // (sr, si) pairs
    #pragma unroll
    for (int p = 0; p < 26; ++p) {
        const int d0 = 2*p;
        float2 w = *reinterpret_cast<const float2*>(&sD0p[o0 + d0]);
        #pragma unroll
        for (int e = 0; e < 2; ++e) {
            const int d = d0 + e;
            const float dv = e ? w.y : w.x;
            if (50 - d >= 0) {                   // d <= 50
                v2f cv = { Cr0[199 + 50 - d], Ci0[199 + 50 - d] };
                s0 += dv * cv;
            }
            if (51 - d <= 50 && 51 - d >= 0) {   // 1 <= d <= 51
                v2f cv = { Cr0[199 + 51 - d], Ci0[199 + 51 - d] };
                s1 += dv * cv;
            }
        }
    }
    const int t = o0 >> 1;
    v4f e0 = sEp[t + 25];          // even sample o0+50
    v4f e1 = sEp[t + 25 + NE2];    // odd  sample o0+51
    acc.x += s0.x*e0.x - s0.y*e0.y;
    acc.y += s0.x*e0.z - s0.y*e0.w;
    acc.z += s1.x*e1.x - s1.y*e1.y;
    acc.w += s1.x*e1.z - s1.y*e1.w;
}

__global__ __launch_bounds__(BLK, 4) void pbc_kernel(
    const float* __restrict__ Er, const float* __restrict__ Ei,
    const float* __restrict__ Cr, const float* __restrict__ Ci,
    float* __restrict__ out)
{
    __shared__ __align__(16) v4f    sEp[NE];         //  5.7 KB (parity-split)
    __shared__ __align__(16) float2 sD[25][ND_AL];   // 61.6 KB (m = 1..25)
    __shared__ __align__(16) float  sD0[ND_AL];      //  1.2 KB (m = 0, real)
    __shared__ __align__(16) float4 sAcc[4][128];    //  8.0 KB partials

    const int b   = blockIdx.y;
    const int k0  = blockIdx.x * NOUT;
    const int tid = threadIdx.x;

    // Opaque VGPR zero: makes C addresses non-provably-uniform so the
    // compiler emits global_load (vmcnt) instead of s_load (SMEM would
    // share lgkmcnt with DS and force lgkmcnt(0) drains in the conv).
    int vz;
    asm volatile("v_mov_b32 %0, 0" : "=v"(vz));
    const float* CrV = Cr + vz;
    const float* CiV = Ci + vz;

    // ---- stage E tile, parity-split: sEp[i] = E[k0+2i], sEp[i+NE2] = E[k0+2i+1]
    const float* erb = Er + (size_t)b * (S_LEN * 2);
    const float* eib = Ei + (size_t)b * (S_LEN * 2);
    if (tid < NE2) {
        const int i  = tid;
        const int kg = k0 + 2 * i;          // even, so kg+1 valid iff kg valid
        v4f rr = {0.f,0.f,0.f,0.f}, ii = {0.f,0.f,0.f,0.f};
        if (kg < S_LEN) {
            rr = *reinterpret_cast<const v4f*>(erb + 2 * kg); // modes of kg, kg+1
            ii = *reinterpret_cast<const v4f*>(eib + 2 * kg);
        }
        sEp[i]       = (v4f){rr.x, ii.x, rr.y, ii.y};   // sample kg
        sEp[i + NE2] = (v4f){rr.z, ii.z, rr.w, ii.w};   // sample kg+1
    }
    __syncthreads();

    // ---- D tiles, pair-at-a-time (one b128 write per 2 values) ----
    // m = 0 (real): 154 pairs, single pass
    if (tid < NDP) {
        const int xp = tid;
        v4f a0 = sEp[xp + 12 + NE2];    // sample 2xp+25 (odd)
        v4f a1 = sEp[xp + 13];          // sample 2xp+26 (even)
        float d0 = a0.x*a0.x + a0.y*a0.y + a0.z*a0.z + a0.w*a0.w;
        float d1 = a1.x*a1.x + a1.y*a1.y + a1.z*a1.z + a1.w*a1.w;
        *reinterpret_cast<float2*>(&sD0[2 * xp]) = make_float2(d0, d1);
    }
    // m = 1..25: 25 x 154 pairs
    for (int idx = tid; idx < 25 * NDP; idx += BLK) {
        const int m1 = idx / NDP;              // 0..24 -> m = m1+1
        const int xp = idx - m1 * NDP;
        const int m  = m1 + 1;
        v4f a0 = sEp[xp + 12 + NE2];           // sample 2xp+25
        v4f a1 = sEp[xp + 13];                 // sample 2xp+26
        const int sb  = 2 * xp + 25 - m;       // sample index of b0
        const int ib0 = (sb >> 1) + (sb & 1) * NE2;
        const int sb1 = sb + 1;
        const int ib1 = (sb1 >> 1) + (sb1 & 1) * NE2;
        v4f b0 = sEp[ib0], b1 = sEp[ib1];
        float gr0 = a0.x*b0.x + a0.y*b0.y + a0.z*b0.z + a0.w*b0.w;
        float gi0 = a0.y*b0.x - a0.x*b0.y + a0.w*b0.z - a0.z*b0.w;
        float gr1 = a1.x*b1.x + a1.y*b1.y + a1.z*b1.z + a1.w*b1.w;
        float gi1 = a1.y*b1.x - a1.x*b1.y + a1.w*b1.z - a1.z*b1.w;
        *reinterpret_cast<v4f*>(&sD[m1][2 * xp]) = (v4f){gr0, gi0, gr1, gi1};
    }
    __syncthreads();

    // ---- conv: 4 groups x 128 threads x 2 outputs ----
    // Groups rebalanced by LDS instruction count (window + epilogue reads):
    // g0: L~66, g1: L~71, g2: L~70, g3: L~88 (was 43/63/89/126).
    const int g  = tid >> 7;            // wave-uniform (2 waves per group)
    const int t  = tid & 127;
    const int o0 = 2 * t;

    float4 acc = make_float4(0.f, 0.f, 0.f, 0.f);
    if (g == 0) {
        convM<1>(sD[0],   sEp, o0, CrV, CiV, acc);
        convM<9>(sD[8],   sEp, o0, CrV, CiV, acc);
        convM<13>(sD[12], sEp, o0, CrV, CiV, acc);
        convM<14>(sD[13], sEp, o0, CrV, CiV, acc);
        convM<19>(sD[18], sEp, o0, CrV, CiV, acc);
    } else if (g == 1) {
        convM<2>(sD[1],   sEp, o0, CrV, CiV, acc);
        convM<3>(sD[2],   sEp, o0, CrV, CiV, acc);
        convM<5>(sD[4],   sEp, o0, CrV, CiV, acc);
        convM<15>(sD[14], sEp, o0, CrV, CiV, acc);
        convM<16>(sD[15], sEp, o0, CrV, CiV, acc);
        convM<20>(sD[19], sEp, o0, CrV, CiV, acc);
    } else if (g == 2) {
        conv0(sD0, sEp, o0, CrV, CiV, acc);
        convM<4>(sD[3],   sEp, o0, CrV, CiV, acc);
        convM<6>(sD[5],   sEp, o0, CrV, CiV, acc);
        convM<7>(sD[6],   sEp, o0, CrV, CiV, acc);
        convM<18>(sD[17], sEp, o0, CrV, CiV, acc);
        convM<21>(sD[20], sEp, o0, CrV, CiV, acc);
    } else {
        convM<8>(sD[7],   sEp, o0, CrV, CiV, acc);
        convM<10>(sD[9],  sEp, o0, CrV, CiV, acc);
        convM<11>(sD[10], sEp, o0, CrV, CiV, acc);
        convM<12>(sD[11], sEp, o0, CrV, CiV, acc);
        convM<17>(sD[16], sEp, o0, CrV, CiV, acc);
        convM<22>(sD[21], sEp, o0, CrV, CiV, acc);
        convM<23>(sD[22], sEp, o0, CrV, CiV, acc);
        convM<24>(sD[23], sEp, o0, CrV, CiV, acc);
        convM<25>(sD[24], sEp, o0, CrV, CiV, acc);
    }
    sAcc[g][t] = acc;
    __syncthreads();

    // ---- combine: threads 0..127 sum the 4 partials and store ----
    if (tid < 128) {
        const int tt = tid;
        const int oo = 2 * tt;
        const int ko = k0 + oo;
        if (ko < SOUT) {
            float4 p0 = sAcc[0][tt], p1 = sAcc[1][tt];
            float4 p2 = sAcc[2][tt], p3 = sAcc[3][tt];
            v4f e0 = sEp[tt + 25];          // sample oo+50 (even)
            v4f e1 = sEp[tt + 25 + NE2];    // sample oo+51 (odd)
            float4 o;
            o.x = e0.x + p0.x + p1.x + p2.x + p3.x;
            o.y = e0.z + p0.y + p1.y + p2.y + p3.y;
            o.z = e1.x + p0.z + p1.z + p2.z + p3.z;
            o.w = e1.z + p0.w + p1.w + p2.w + p3.w;
            *reinterpret_cast<float4*>(out + ((size_t)b * SOUT + ko) * 2) = o;
        }
    }
}

extern "C" void kernel_launch(void* const* d_in, const int* in_sizes, int n_in,
                              void* d_out, int out_size, void* d_ws, size_t ws_size,
                              hipStream_t stream) {
    const float* Er = (const float*)d_in[0];
    const float* Ei = (const float*)d_in[1];
    const float* Cr = (const float*)d_in[2];   // [4, 449], row 0 used
    const float* Ci = (const float*)d_in[3];
    float* out = (float*)d_out;                // [8, 16284, 2] float32 (Re)

    dim3 grid((SOUT + NOUT - 1) / NOUT, 8);
    pbc_kernel<<<grid, BLK, 0, stream>>>(Er, Ei, Cr, Ci, out);
}

// Round 14
// 19.029 us; speedup vs baseline: 1.7119x; 1.7119x over previous
//
#include <hip/hip_runtime.h>

// PBC nonlinear compensation, D-factorized, single-conv-phase, R=2 + b128,
// packed-FP32 conv + parity-split E + C-in-LDS (broadcast ds_read):
//   O[b,k,i] = E[b,k,i] + sum_m sm(k;m) * E[b,k-m,i]        (Re part stored)
//   sm(k;m)  = sum_n C[m,n] * D_m[k-n]
//   D_m[x]   = sum_j E_j[x] * conj(E_j[x-m]),  D_{-m}[x] = conj(D_m[x+m])
//
// R13 lesson: C via per-lane VMEM = 64x redundant traffic (32.6us). R12
// lesson: C via s_load = SMEM/DS lgkmcnt mixing, out-of-order SMEM forces
// lgkmcnt(0) drains between ds_reads (latency-bound at 17.8us, pipes only
// ~37% busy). Fix: C staged in LDS; wave-uniform ds_read_b64 broadcasts are
// conflict-free, in-order with window reads on one DS queue -> partial
// lgkmcnt(N) waits, deep pipelining.

typedef float v2f __attribute__((ext_vector_type(2)));
typedef float v4f __attribute__((ext_vector_type(4)));

#define S_LEN 16384
#define SOUT  16284          // S - 2*L
#define BLK   512
#define NOUT  256            // outputs per block
#define NE    356            // staged E samples: [k0, k0+355]
#define NE2   178            // NE/2 (parity-split halves)
#define ND    307            // D tile: x in [k0+25, k0+331]
#define ND_AL 308            // row stride (pair-writable, 16B-aligned rows)
#define NDP   154            // ND_AL/2 pairs per row
#define T_CNT 449

constexpr int LIMS[26] = {25,25,12,8,6,5,4,3,3,2,2,2,2,
                          1,1,1,1,1,1,1,1,1,1,1,1,1};
constexpr int TS[51] = {
      0,  3,  6,  9, 12, 15, 18, 21, 24, 27, 30, 33, 36,
     39, 44, 49, 54, 59, 66, 73, 82, 93,106,123,148,199,
    250,301,326,343,356,367,376,383,390,395,400,405,410,
    413,416,419,422,425,428,431,434,437,440,443,446};

template<int M>
__device__ __forceinline__ void convM(
    const float2* __restrict__ sDm, const v4f* __restrict__ sEp,
    const float2* __restrict__ sC, int o0, float4& acc)
{
    constexpr int lim = LIMS[M];
    constexpr int tp  = TS[25 + M];
    constexpr int tn  = TS[25 - M];
    constexpr int A   = 25 + lim;

    // packed accumulators: S{x,y}{P,N}{out0,out1}
    v2f SxP0 = {0.f,0.f}, SyP0 = {0.f,0.f}, SxP1 = {0.f,0.f}, SyP1 = {0.f,0.f};
    v2f SxN0 = {0.f,0.f}, SyN0 = {0.f,0.f}, SxN1 = {0.f,0.f}, SyN1 = {0.f,0.f};

#define TAP(dconst, dd)                                                     \
    {                                                                       \
        const int d_ = (dconst);                                            \
        if (A - d_ >= 0 && A - d_ <= 2*lim) {                               \
            const float2 c = sC[tp + A - d_];                               \
            SxP0 += c.x * (dd);  SyP0 += c.y * (dd);                        \
        }                                                                   \
        if (A + 1 - d_ >= 0 && A + 1 - d_ <= 2*lim) {                       \
            const float2 c = sC[tp + A+1-d_];                               \
            SxP1 += c.x * (dd);  SyP1 += c.y * (dd);                        \
        }                                                                   \
        if (A + M - d_ >= 0 && A + M - d_ <= 2*lim) {                       \
            const float2 c = sC[tn + A+M-d_];                               \
            SxN0 += c.x * (dd);  SyN0 += c.y * (dd);                        \
        }                                                                   \
        if (A + M + 1 - d_ >= 0 && A + M + 1 - d_ <= 2*lim) {               \
            const float2 c = sC[tn + A+M+1-d_];                             \
            SxN1 += c.x * (dd);  SyN1 += c.y * (dd);                        \
        }                                                                   \
    }

    if constexpr (M < 2*lim + 4) {
        // merged window: d in [25-lim, 26+lim+M]
        constexpr int dlo = (25 - lim) & ~1;
        constexpr int dhi = 26 + lim + M;
        constexpr int NP  = (dhi - dlo) / 2 + 1;
        #pragma unroll
        for (int p = 0; p < NP; ++p) {
            const int d0 = dlo + 2*p;
            v4f w = *reinterpret_cast<const v4f*>(&sDm[o0 + d0]);
            TAP(d0,     w.xy)
            TAP(d0 + 1, w.zw)
        }
    } else {
        // +m window: d in [25-lim, 26+lim]
        {
            constexpr int dlo = (25 - lim) & ~1;
            constexpr int dhi = 26 + lim;
            constexpr int NP  = (dhi - dlo) / 2 + 1;
            #pragma unroll
            for (int p = 0; p < NP; ++p) {
                const int d0 = dlo + 2*p;
                v4f w = *reinterpret_cast<const v4f*>(&sDm[o0 + d0]);
                #pragma unroll
                for (int e = 0; e < 2; ++e) {
                    const int d = d0 + e;
                    const v2f dd = e ? w.zw : w.xy;
                    if (A - d >= 0 && A - d <= 2*lim) {
                        const float2 c = sC[tp + A - d];
                        SxP0 += c.x * dd;  SyP0 += c.y * dd;
                    }
                    if (A + 1 - d >= 0 && A + 1 - d <= 2*lim) {
                        const float2 c = sC[tp + A+1-d];
                        SxP1 += c.x * dd;  SyP1 += c.y * dd;
                    }
                }
            }
        }
        // -m window: d in [25+M-lim, 26+M+lim]
        {
            constexpr int dlo = (25 + M - lim) & ~1;
            constexpr int dhi = 26 + M + lim;
            constexpr int NP  = (dhi - dlo) / 2 + 1;
            #pragma unroll
            for (int p = 0; p < NP; ++p) {
                const int d0 = dlo + 2*p;
                v4f w = *reinterpret_cast<const v4f*>(&sDm[o0 + d0]);
                #pragma unroll
                for (int e = 0; e < 2; ++e) {
                    const int d = d0 + e;
                    const v2f dd = e ? w.zw : w.xy;
                    if (A + M - d >= 0 && A + M - d <= 2*lim) {
                        const float2 c = sC[tn + A+M-d];
                        SxN0 += c.x * dd;  SyN0 += c.y * dd;
                    }
                    if (A + M + 1 - d >= 0 && A + M + 1 - d <= 2*lim) {
                        const float2 c = sC[tn + A+M+1-d];
                        SxN1 += c.x * dd;  SyN1 += c.y * dd;
                    }
                }
            }
        }
    }
#undef TAP

    // sign combination (deferred): +m: sr=Sx.x-Sy.y, si=Sx.y+Sy.x
    //                              -m (conj D): sr=Sx.x+Sy.y, si=Sy.x-Sx.y
    const float s0pr = SxP0.x - SyP0.y, s0pi = SxP0.y + SyP0.x;
    const float s1pr = SxP1.x - SyP1.y, s1pi = SxP1.y + SyP1.x;
    const float s0nr = SxN0.x + SyN0.y, s0ni = SyN0.x - SxN0.y;
    const float s1nr = SxN1.x + SyN1.y, s1ni = SyN1.x - SxN1.y;

    // parity-split E reads: all are sEp[t + const] (contiguous, aligned)
    const int t = o0 >> 1;
    v4f ep0, ep1, en0, en1;
    if constexpr ((M & 1) == 0) {
        ep0 = sEp[t + (50 - M)/2];          // even sample o0+50-M
        ep1 = sEp[t + (50 - M)/2 + NE2];    // odd  sample o0+51-M
        en0 = sEp[t + (50 + M)/2];
        en1 = sEp[t + (50 + M)/2 + NE2];
    } else {
        ep0 = sEp[t + (49 - M)/2 + NE2];    // odd  sample o0+50-M
        ep1 = sEp[t + (51 - M)/2];          // even sample o0+51-M
        en0 = sEp[t + (49 + M)/2 + NE2];
        en1 = sEp[t + (51 + M)/2];
    }
    acc.x += s0pr*ep0.x - s0pi*ep0.y + s0nr*en0.x - s0ni*en0.y;
    acc.y += s0pr*ep0.z - s0pi*ep0.w + s0nr*en0.z - s0ni*en0.w;
    acc.z += s1pr*ep1.x - s1pi*ep1.y + s1nr*en1.x - s1ni*en1.y;
    acc.w += s1pr*ep1.z - s1pi*ep1.w + s1nr*en1.z - s1ni*en1.w;
}

// m = 0: D real, taps j=0..50, c = sC[199+j]; out0: j = 50-d, out1: j = 51-d.
__device__ __forceinline__ void conv0(
    const float* __restrict__ sD0p, const v4f* __restrict__ sEp,
    const float2* __restrict__ sC, int o0, float4& acc)
{
    v2f s0 = {0.f, 0.f}, s1 = {0.f, 0.f};   // (sr, si) pairs
    #pragma unroll
    for (int p = 0; p < 26; ++p) {
        const int d0 = 2*p;
        float2 w = *reinterpret_cast<const float2*>(&sD0p[o0 + d0]);
        #pragma unroll
        for (int e = 0; e < 2; ++e) {
            const int d = d0 + e;
            const float dv = e ? w.y : w.x;
            if (50 - d >= 0) {                   // d <= 50
                const float2 c = sC[199 + 50 - d];
                s0 += dv * (v2f){c.x, c.y};
            }
            if (51 - d <= 50 && 51 - d >= 0) {   // 1 <= d <= 51
                const float2 c = sC[199 + 51 - d];
                s1 += dv * (v2f){c.x, c.y};
            }
        }
    }
    const int t = o0 >> 1;
    v4f e0 = sEp[t + 25];          // even sample o0+50
    v4f e1 = sEp[t + 25 + NE2];    // odd  sample o0+51
    acc.x += s0.x*e0.x - s0.y*e0.y;
    acc.y += s0.x*e0.z - s0.y*e0.w;
    acc.z += s1.x*e1.x - s1.y*e1.y;
    acc.w += s1.x*e1.z - s1.y*e1.w;
}

__global__ __launch_bounds__(BLK, 4) void pbc_kernel(
    const float* __restrict__ Er, const float* __restrict__ Ei,
    const float* __restrict__ Cr, const float* __restrict__ Ci,
    float* __restrict__ out)
{
    __shared__ __align__(16) v4f    sEp[NE];         //  5.7 KB (parity-split)
    __shared__ __align__(16) float2 sD[25][ND_AL];   // 61.6 KB (m = 1..25)
    __shared__ __align__(16) float  sD0[ND_AL];      //  1.2 KB (m = 0, real)
    __shared__ __align__(16) float2 sC[T_CNT + 1];   //  3.6 KB coefficients
    __shared__ __align__(16) float4 sAcc[3][128];    //  6.0 KB partials g1..g3
    // total 78.1 KB -> 2 blocks/CU

    const int b   = blockIdx.y;
    const int k0  = blockIdx.x * NOUT;
    const int tid = threadIdx.x;

    // ---- stage E tile (parity-split) + C ----
    const float* erb = Er + (size_t)b * (S_LEN * 2);
    const float* eib = Ei + (size_t)b * (S_LEN * 2);
    if (tid < NE2) {
        const int i  = tid;
        const int kg = k0 + 2 * i;          // even, so kg+1 valid iff kg valid
        v4f rr = {0.f,0.f,0.f,0.f}, ii = {0.f,0.f,0.f,0.f};
        if (kg < S_LEN) {
            rr = *reinterpret_cast<const v4f*>(erb + 2 * kg); // modes of kg, kg+1
            ii = *reinterpret_cast<const v4f*>(eib + 2 * kg);
        }
        sEp[i]       = (v4f){rr.x, ii.x, rr.y, ii.y};   // sample kg
        sEp[i + NE2] = (v4f){rr.z, ii.z, rr.w, ii.w};   // sample kg+1
    }
    for (int t = tid; t < T_CNT; t += BLK)
        sC[t] = make_float2(Cr[t], Ci[t]);
    __syncthreads();

    // ---- D tiles, pair-at-a-time (one b128 write per 2 values) ----
    // m = 0 (real): 154 pairs, single pass
    if (tid < NDP) {
        const int xp = tid;
        v4f a0 = sEp[xp + 12 + NE2];    // sample 2xp+25 (odd)
        v4f a1 = sEp[xp + 13];          // sample 2xp+26 (even)
        float d0 = a0.x*a0.x + a0.y*a0.y + a0.z*a0.z + a0.w*a0.w;
        float d1 = a1.x*a1.x + a1.y*a1.y + a1.z*a1.z + a1.w*a1.w;
        *reinterpret_cast<float2*>(&sD0[2 * xp]) = make_float2(d0, d1);
    }
    // m = 1..25: 25 x 154 pairs
    for (int idx = tid; idx < 25 * NDP; idx += BLK) {
        const int m1 = idx / NDP;              // 0..24 -> m = m1+1
        const int xp = idx - m1 * NDP;
        const int m  = m1 + 1;
        v4f a0 = sEp[xp + 12 + NE2];           // sample 2xp+25
        v4f a1 = sEp[xp + 13];                 // sample 2xp+26
        const int sb  = 2 * xp + 25 - m;       // sample index of b0
        const int ib0 = (sb >> 1) + (sb & 1) * NE2;
        const int sb1 = sb + 1;
        const int ib1 = (sb1 >> 1) + (sb1 & 1) * NE2;
        v4f b0 = sEp[ib0], b1 = sEp[ib1];
        float gr0 = a0.x*b0.x + a0.y*b0.y + a0.z*b0.z + a0.w*b0.w;
        float gi0 = a0.y*b0.x - a0.x*b0.y + a0.w*b0.z - a0.z*b0.w;
        float gr1 = a1.x*b1.x + a1.y*b1.y + a1.z*b1.z + a1.w*b1.w;
        float gi1 = a1.y*b1.x - a1.x*b1.y + a1.w*b1.z - a1.z*b1.w;
        *reinterpret_cast<v4f*>(&sD[m1][2 * xp]) = (v4f){gr0, gi0, gr1, gi1};
    }
    __syncthreads();

    // ---- conv: 4 groups x 128 threads x 2 outputs (balanced by LDS cost) ----
    const int g  = tid >> 7;            // wave-uniform (2 waves per group)
    const int t  = tid & 127;
    const int o0 = 2 * t;

    float4 acc = make_float4(0.f, 0.f, 0.f, 0.f);
    if (g == 0) {
        convM<1>(sD[0],   sEp, sC, o0, acc);
        convM<9>(sD[8],   sEp, sC, o0, acc);
        convM<13>(sD[12], sEp, sC, o0, acc);
        convM<14>(sD[13], sEp, sC, o0, acc);
        convM<19>(sD[18], sEp, sC, o0, acc);
    } else if (g == 1) {
        convM<2>(sD[1],   sEp, sC, o0, acc);
        convM<3>(sD[2],   sEp, sC, o0, acc);
        convM<5>(sD[4],   sEp, sC, o0, acc);
        convM<15>(sD[14], sEp, sC, o0, acc);
        convM<16>(sD[15], sEp, sC, o0, acc);
        convM<20>(sD[19], sEp, sC, o0, acc);
    } else if (g == 2) {
        conv0(sD0, sEp, sC, o0, acc);
        convM<4>(sD[3],   sEp, sC, o0, acc);
        convM<6>(sD[5],   sEp, sC, o0, acc);
        convM<7>(sD[6],   sEp, sC, o0, acc);
        convM<18>(sD[17], sEp, sC, o0, acc);
        convM<21>(sD[20], sEp, sC, o0, acc);
    } else {
        convM<8>(sD[7],   sEp, sC, o0, acc);
        convM<10>(sD[9],  sEp, sC, o0, acc);
        convM<11>(sD[10], sEp, sC, o0, acc);
        convM<12>(sD[11], sEp, sC, o0, acc);
        convM<17>(sD[16], sEp, sC, o0, acc);
        convM<22>(sD[21], sEp, sC, o0, acc);
        convM<23>(sD[22], sEp, sC, o0, acc);
        convM<24>(sD[23], sEp, sC, o0, acc);
        convM<25>(sD[24], sEp, sC, o0, acc);
    }
    if (g > 0) sAcc[g - 1][t] = acc;
    __syncthreads();

    // ---- combine: g0 (threads 0..127) adds its own acc + 3 partials ----
    if (tid < 128) {
        const int tt = tid;
        const int oo = 2 * tt;
        const int ko = k0 + oo;
        if (ko < SOUT) {
            float4 p1 = sAcc[0][tt], p2 = sAcc[1][tt], p3 = sAcc[2][tt];
            v4f e0 = sEp[tt + 25];          // sample oo+50 (even)
            v4f e1 = sEp[tt + 25 + NE2];    // sample oo+51 (odd)
            float4 o;
            o.x = e0.x + acc.x + p1.x + p2.x + p3.x;
            o.y = e0.z + acc.y + p1.y + p2.y + p3.y;
            o.z = e1.x + acc.z + p1.z + p2.z + p3.z;
            o.w = e1.z + acc.w + p1.w + p2.w + p3.w;
            *reinterpret_cast<float4*>(out + ((size_t)b * SOUT + ko) * 2) = o;
        }
    }
}

extern "C" void kernel_launch(void* const* d_in, const int* in_sizes, int n_in,
                              void* d_out, int out_size, void* d_ws, size_t ws_size,
                              hipStream_t stream) {
    const float* Er = (const float*)d_in[0];
    const float* Ei = (const float*)d_in[1];
    const float* Cr = (const float*)d_in[2];   // [4, 449], row 0 used
    const float* Ci = (const float*)d_in[3];
    float* out = (float*)d_out;                // [8, 16284, 2] float32 (Re)

    dim3 grid((SOUT + NOUT - 1) / NOUT, 8);
    pbc_kernel<<<grid, BLK, 0, stream>>>(Er, Ei, Cr, Ci, out);
}

// Round 15
// 17.343 us; speedup vs baseline: 1.8784x; 1.0972x over previous
//
#include <hip/hip_runtime.h>

// PBC nonlinear compensation, D-factorized, single-conv-phase, R=2 + b128,
// packed-FP32 conv + parity-split E + C-via-s_load + BALANCED m-groups:
//   O[b,k,i] = E[b,k,i] + sum_m sm(k;m) * E[b,k-m,i]        (Re part stored)
//   sm(k;m)  = sum_n C[m,n] * D_m[k-n]
//   D_m[x]   = sum_j E_j[x] * conj(E_j[x-m]),  D_{-m}[x] = conj(D_m[x+m])
//
// R13: C per-lane VMEM = 64x traffic (32.6us). R14: C in LDS = +230 DS
// issues/thread (19.0us). R12 (C s_load) = 17.8us is the winner; this round
// keeps R12 byte-for-byte except (a) m-groups balanced by LDS-instruction
// cost (max 130 -> ~80 per thread; conv phase is gated by the max group),
// (b) conv0 reads sD0 as aligned v4f (13 b128 instead of 26 b64).

typedef float v2f __attribute__((ext_vector_type(2)));
typedef float v4f __attribute__((ext_vector_type(4)));

#define S_LEN 16384
#define SOUT  16284          // S - 2*L
#define BLK   512
#define NOUT  256            // outputs per block
#define NE    356            // staged E samples: [k0, k0+355]
#define NE2   178            // NE/2 (parity-split halves)
#define ND    307            // D tile: x in [k0+25, k0+331]
#define ND_AL 308            // row stride (pair-writable, 16B-aligned rows)
#define NDP   154            // ND_AL/2 pairs per row

constexpr int LIMS[26] = {25,25,12,8,6,5,4,3,3,2,2,2,2,
                          1,1,1,1,1,1,1,1,1,1,1,1,1};
constexpr int TS[51] = {
      0,  3,  6,  9, 12, 15, 18, 21, 24, 27, 30, 33, 36,
     39, 44, 49, 54, 59, 66, 73, 82, 93,106,123,148,199,
    250,301,326,343,356,367,376,383,390,395,400,405,410,
    413,416,419,422,425,428,431,434,437,440,443,446};

template<int M>
__device__ __forceinline__ void convM(
    const float2* __restrict__ sDm, const v4f* __restrict__ sEp,
    int o0, const float* __restrict__ Cr0, const float* __restrict__ Ci0,
    float4& acc)
{
    constexpr int lim = LIMS[M];
    constexpr int tp  = TS[25 + M];
    constexpr int tn  = TS[25 - M];
    constexpr int A   = 25 + lim;

    // packed accumulators: S{x,y}{P,N}{out0,out1}
    v2f SxP0 = {0.f,0.f}, SyP0 = {0.f,0.f}, SxP1 = {0.f,0.f}, SyP1 = {0.f,0.f};
    v2f SxN0 = {0.f,0.f}, SyN0 = {0.f,0.f}, SxN1 = {0.f,0.f}, SyN1 = {0.f,0.f};

#define TAP(dconst, dd)                                                     \
    {                                                                       \
        const int d_ = (dconst);                                            \
        if (A - d_ >= 0 && A - d_ <= 2*lim) {                               \
            const float cx = Cr0[tp + A - d_], cy = Ci0[tp + A - d_];       \
            SxP0 += cx * (dd);  SyP0 += cy * (dd);                          \
        }                                                                   \
        if (A + 1 - d_ >= 0 && A + 1 - d_ <= 2*lim) {                       \
            const float cx = Cr0[tp + A+1-d_], cy = Ci0[tp + A+1-d_];       \
            SxP1 += cx * (dd);  SyP1 += cy * (dd);                          \
        }                                                                   \
        if (A + M - d_ >= 0 && A + M - d_ <= 2*lim) {                       \
            const float cx = Cr0[tn + A+M-d_], cy = Ci0[tn + A+M-d_];       \
            SxN0 += cx * (dd);  SyN0 += cy * (dd);                          \
        }                                                                   \
        if (A + M + 1 - d_ >= 0 && A + M + 1 - d_ <= 2*lim) {               \
            const float cx = Cr0[tn + A+M+1-d_], cy = Ci0[tn + A+M+1-d_];   \
            SxN1 += cx * (dd);  SyN1 += cy * (dd);                          \
        }                                                                   \
    }

    if constexpr (M < 2*lim + 4) {
        // merged window: d in [25-lim, 26+lim+M]
        constexpr int dlo = (25 - lim) & ~1;
        constexpr int dhi = 26 + lim + M;
        constexpr int NP  = (dhi - dlo) / 2 + 1;
        #pragma unroll
        for (int p = 0; p < NP; ++p) {
            const int d0 = dlo + 2*p;
            v4f w = *reinterpret_cast<const v4f*>(&sDm[o0 + d0]);
            TAP(d0,     w.xy)
            TAP(d0 + 1, w.zw)
        }
    } else {
        // +m window: d in [25-lim, 26+lim]
        {
            constexpr int dlo = (25 - lim) & ~1;
            constexpr int dhi = 26 + lim;
            constexpr int NP  = (dhi - dlo) / 2 + 1;
            #pragma unroll
            for (int p = 0; p < NP; ++p) {
                const int d0 = dlo + 2*p;
                v4f w = *reinterpret_cast<const v4f*>(&sDm[o0 + d0]);
                #pragma unroll
                for (int e = 0; e < 2; ++e) {
                    const int d = d0 + e;
                    const v2f dd = e ? w.zw : w.xy;
                    if (A - d >= 0 && A - d <= 2*lim) {
                        const float cx = Cr0[tp + A - d], cy = Ci0[tp + A - d];
                        SxP0 += cx * dd;  SyP0 += cy * dd;
                    }
                    if (A + 1 - d >= 0 && A + 1 - d <= 2*lim) {
                        const float cx = Cr0[tp + A+1-d], cy = Ci0[tp + A+1-d];
                        SxP1 += cx * dd;  SyP1 += cy * dd;
                    }
                }
            }
        }
        // -m window: d in [25+M-lim, 26+M+lim]
        {
            constexpr int dlo = (25 + M - lim) & ~1;
            constexpr int dhi = 26 + M + lim;
            constexpr int NP  = (dhi - dlo) / 2 + 1;
            #pragma unroll
            for (int p = 0; p < NP; ++p) {
                const int d0 = dlo + 2*p;
                v4f w = *reinterpret_cast<const v4f*>(&sDm[o0 + d0]);
                #pragma unroll
                for (int e = 0; e < 2; ++e) {
                    const int d = d0 + e;
                    const v2f dd = e ? w.zw : w.xy;
                    if (A + M - d >= 0 && A + M - d <= 2*lim) {
                        const float cx = Cr0[tn + A+M-d], cy = Ci0[tn + A+M-d];
                        SxN0 += cx * dd;  SyN0 += cy * dd;
                    }
                    if (A + M + 1 - d >= 0 && A + M + 1 - d <= 2*lim) {
                        const float cx = Cr0[tn + A+M+1-d], cy = Ci0[tn + A+M+1-d];
                        SxN1 += cx * dd;  SyN1 += cy * dd;
                    }
                }
            }
        }
    }
#undef TAP

    // sign combination (deferred): +m: sr=Sx.x-Sy.y, si=Sx.y+Sy.x
    //                              -m (conj D): sr=Sx.x+Sy.y, si=Sy.x-Sx.y
    const float s0pr = SxP0.x - SyP0.y, s0pi = SxP0.y + SyP0.x;
    const float s1pr = SxP1.x - SyP1.y, s1pi = SxP1.y + SyP1.x;
    const float s0nr = SxN0.x + SyN0.y, s0ni = SyN0.x - SxN0.y;
    const float s1nr = SxN1.x + SyN1.y, s1ni = SyN1.x - SxN1.y;

    // parity-split E reads: all are sEp[t + const] (contiguous, aligned)
    const int t = o0 >> 1;
    v4f ep0, ep1, en0, en1;
    if constexpr ((M & 1) == 0) {
        ep0 = sEp[t + (50 - M)/2];          // even sample o0+50-M
        ep1 = sEp[t + (50 - M)/2 + NE2];    // odd  sample o0+51-M
        en0 = sEp[t + (50 + M)/2];
        en1 = sEp[t + (50 + M)/2 + NE2];
    } else {
        ep0 = sEp[t + (49 - M)/2 + NE2];    // odd  sample o0+50-M
        ep1 = sEp[t + (51 - M)/2];          // even sample o0+51-M
        en0 = sEp[t + (49 + M)/2 + NE2];
        en1 = sEp[t + (51 + M)/2];
    }
    acc.x += s0pr*ep0.x - s0pi*ep0.y + s0nr*en0.x - s0ni*en0.y;
    acc.y += s0pr*ep0.z - s0pi*ep0.w + s0nr*en0.z - s0ni*en0.w;
    acc.z += s1pr*ep1.x - s1pi*ep1.y + s1nr*en1.x - s1ni*en1.y;
    acc.w += s1pr*ep1.z - s1pi*ep1.w + s1nr*en1.z - s1ni*en1.w;
}

// m = 0: D real, taps j=0..50, c = C[199+j]; out0: j = 50-d, out1: j = 51-d.
// Reads sD0 as aligned v4f (13 b128 reads covering d = 0..51).
__device__ __forceinline__ void conv0(
    const float* __restrict__ sD0p, const v4f* __restrict__ sEp,
    int o0, const float* __restrict__ Cr0, const float* __restrict__ Ci0,
    float4& acc)
{
    v2f s0 = {0.f, 0.f}, s1 = {0.f, 0.f};   // (sr, si) pairs
    #pragma unroll
    for (int p = 0; p < 13; ++p) {
        const int d0 = 4*p;
        v4f w = *reinterpret_cast<const v4f*>(&sD0p[o0 + d0]);
        #pragma unroll
        for (int e = 0; e < 4; ++e) {
            const int d = d0 + e;
            const float dv = (e == 0) ? w.x : (e == 1) ? w.y : (e == 2) ? w.z : w.w;
            if (50 - d >= 0) {                   // d <= 50
                v2f cv = { Cr0[199 + 50 - d], Ci0[199 + 50 - d] };
                s0 += dv * cv;
            }
            if (51 - d >= 0 && 51 - d <= 50) {   // 1 <= d <= 51
                v2f cv = { Cr0[199 + 51 - d], Ci0[199 + 51 - d] };
                s1 += dv * cv;
            }
        }
    }
    const int t = o0 >> 1;
    v4f e0 = sEp[t + 25];          // even sample o0+50
    v4f e1 = sEp[t + 25 + NE2];    // odd  sample o0+51
    acc.x += s0.x*e0.x - s0.y*e0.y;
    acc.y += s0.x*e0.z - s0.y*e0.w;
    acc.z += s1.x*e1.x - s1.y*e1.y;
    acc.w += s1.x*e1.z - s1.y*e1.w;
}

__global__ __launch_bounds__(BLK, 4) void pbc_kernel(
    const float* __restrict__ Er, const float* __restrict__ Ei,
    const float* __restrict__ Cr, const float* __restrict__ Ci,
    float* __restrict__ out)
{
    __shared__ __align__(16) v4f    sEp[NE];         //  5.7 KB (parity-split)
    __shared__ __align__(16) float2 sD[25][ND_AL];   // 61.6 KB (m = 1..25)
    __shared__ __align__(16) float  sD0[ND_AL];      //  1.2 KB (m = 0, real)
    __shared__ __align__(16) float4 sAcc[4][128];    //  8.0 KB partials

    const int b   = blockIdx.y;
    const int k0  = blockIdx.x * NOUT;
    const int tid = threadIdx.x;

    // ---- stage E tile, parity-split: sEp[i] = E[k0+2i], sEp[i+NE2] = E[k0+2i+1]
    const float* erb = Er + (size_t)b * (S_LEN * 2);
    const float* eib = Ei + (size_t)b * (S_LEN * 2);
    if (tid < NE2) {
        const int i  = tid;
        const int kg = k0 + 2 * i;          // even, so kg+1 valid iff kg valid
        v4f rr = {0.f,0.f,0.f,0.f}, ii = {0.f,0.f,0.f,0.f};
        if (kg < S_LEN) {
            rr = *reinterpret_cast<const v4f*>(erb + 2 * kg); // modes of kg, kg+1
            ii = *reinterpret_cast<const v4f*>(eib + 2 * kg);
        }
        sEp[i]       = (v4f){rr.x, ii.x, rr.y, ii.y};   // sample kg
        sEp[i + NE2] = (v4f){rr.z, ii.z, rr.w, ii.w};   // sample kg+1
    }
    __syncthreads();

    // ---- D tiles, pair-at-a-time (one b128 write per 2 values) ----
    // m = 0 (real): 154 pairs, single pass
    if (tid < NDP) {
        const int xp = tid;
        v4f a0 = sEp[xp + 12 + NE2];    // sample 2xp+25 (odd)
        v4f a1 = sEp[xp + 13];          // sample 2xp+26 (even)
        float d0 = a0.x*a0.x + a0.y*a0.y + a0.z*a0.z + a0.w*a0.w;
        float d1 = a1.x*a1.x + a1.y*a1.y + a1.z*a1.z + a1.w*a1.w;
        *reinterpret_cast<float2*>(&sD0[2 * xp]) = make_float2(d0, d1);
    }
    // m = 1..25: 25 x 154 pairs
    for (int idx = tid; idx < 25 * NDP; idx += BLK) {
        const int m1 = idx / NDP;              // 0..24 -> m = m1+1
        const int xp = idx - m1 * NDP;
        const int m  = m1 + 1;
        v4f a0 = sEp[xp + 12 + NE2];           // sample 2xp+25
        v4f a1 = sEp[xp + 13];                 // sample 2xp+26
        const int sb  = 2 * xp + 25 - m;       // sample index of b0
        const int ib0 = (sb >> 1) + (sb & 1) * NE2;
        const int sb1 = sb + 1;
        const int ib1 = (sb1 >> 1) + (sb1 & 1) * NE2;
        v4f b0 = sEp[ib0], b1 = sEp[ib1];
        float gr0 = a0.x*b0.x + a0.y*b0.y + a0.z*b0.z + a0.w*b0.w;
        float gi0 = a0.y*b0.x - a0.x*b0.y + a0.w*b0.z - a0.z*b0.w;
        float gr1 = a1.x*b1.x + a1.y*b1.y + a1.z*b1.z + a1.w*b1.w;
        float gi1 = a1.y*b1.x - a1.x*b1.y + a1.w*b1.z - a1.z*b1.w;
        *reinterpret_cast<v4f*>(&sD[m1][2 * xp]) = (v4f){gr0, gi0, gr1, gi1};
    }
    __syncthreads();

    // ---- conv: 4 groups x 128 threads x 2 outputs ----
    // Groups balanced by LDS-instruction cost (window pairs + epilogue):
    // g0 ~73.5, g1 ~73, g2 ~74.5, g3 ~79.5 (R12 was 40/55/75/130).
    const int g  = tid >> 7;            // wave-uniform (2 waves per group)
    const int t  = tid & 127;
    const int o0 = 2 * t;

    float4 acc = make_float4(0.f, 0.f, 0.f, 0.f);
    if (g == 0) {
        convM<1>(sD[0],   sEp, o0, Cr, Ci, acc);
        convM<13>(sD[12], sEp, o0, Cr, Ci, acc);
        convM<14>(sD[13], sEp, o0, Cr, Ci, acc);
        convM<15>(sD[14], sEp, o0, Cr, Ci, acc);
        convM<16>(sD[15], sEp, o0, Cr, Ci, acc);
        convM<17>(sD[16], sEp, o0, Cr, Ci, acc);
    } else if (g == 1) {
        convM<2>(sD[1],   sEp, o0, Cr, Ci, acc);
        convM<4>(sD[3],   sEp, o0, Cr, Ci, acc);
        convM<7>(sD[6],   sEp, o0, Cr, Ci, acc);
        convM<9>(sD[8],   sEp, o0, Cr, Ci, acc);
        convM<18>(sD[17], sEp, o0, Cr, Ci, acc);
        convM<19>(sD[18], sEp, o0, Cr, Ci, acc);
    } else if (g == 2) {
        conv0(sD0, sEp, o0, Cr, Ci, acc);
        convM<3>(sD[2],   sEp, o0, Cr, Ci, acc);
        convM<8>(sD[7],   sEp, o0, Cr, Ci, acc);
        convM<10>(sD[9],  sEp, o0, Cr, Ci, acc);
        convM<12>(sD[11], sEp, o0, Cr, Ci, acc);
        convM<20>(sD[19], sEp, o0, Cr, Ci, acc);
    } else {
        convM<5>(sD[4],   sEp, o0, Cr, Ci, acc);
        convM<6>(sD[5],   sEp, o0, Cr, Ci, acc);
        convM<11>(sD[10], sEp, o0, Cr, Ci, acc);
        convM<21>(sD[20], sEp, o0, Cr, Ci, acc);
        convM<22>(sD[21], sEp, o0, Cr, Ci, acc);
        convM<23>(sD[22], sEp, o0, Cr, Ci, acc);
        convM<24>(sD[23], sEp, o0, Cr, Ci, acc);
        convM<25>(sD[24], sEp, o0, Cr, Ci, acc);
    }
    sAcc[g][t] = acc;
    __syncthreads();

    // ---- combine: threads 0..127 sum the 4 partials and store ----
    if (tid < 128) {
        const int tt = tid;
        const int oo = 2 * tt;
        const int ko = k0 + oo;
        if (ko < SOUT) {
            float4 p0 = sAcc[0][tt], p1 = sAcc[1][tt];
            float4 p2 = sAcc[2][tt], p3 = sAcc[3][tt];
            v4f e0 = sEp[tt + 25];          // sample oo+50 (even)
            v4f e1 = sEp[tt + 25 + NE2];    // sample oo+51 (odd)
            float4 o;
            o.x = e0.x + p0.x + p1.x + p2.x + p3.x;
            o.y = e0.z + p0.y + p1.y + p2.y + p3.y;
            o.z = e1.x + p0.z + p1.z + p2.z + p3.z;
            o.w = e1.z + p0.w + p1.w + p2.w + p3.w;
            *reinterpret_cast<float4*>(out + ((size_t)b * SOUT + ko) * 2) = o;
        }
    }
}

extern "C" void kernel_launch(void* const* d_in, const int* in_sizes, int n_in,
                              void* d_out, int out_size, void* d_ws, size_t ws_size,
                              hipStream_t stream) {
    const float* Er = (const float*)d_in[0];
    const float* Ei = (const float*)d_in[1];
    const float* Cr = (const float*)d_in[2];   // [4, 449], row 0 used
    const float* Ci = (const float*)d_in[3];
    float* out = (float*)d_out;                // [8, 16284, 2] float32 (Re)

    dim3 grid((SOUT + NOUT - 1) / NOUT, 8);
    pbc_kernel<<<grid, BLK, 0, stream>>>(Er, Ei, Cr, Ci, out);
}

// Round 16
// 16.080 us; speedup vs baseline: 2.0259x; 1.0785x over previous
//
#include <hip/hip_runtime.h>

// PBC nonlinear compensation, D-factorized, single-conv-phase:
// R=4 outputs/thread + bf16-PACKED D tiles (u32 = {bf16 re, bf16 im}):
//   O[b,k,i] = E[b,k,i] + sum_m sm(k;m) * E[b,k-m,i]        (Re part stored)
//   sm(k;m)  = sum_n C[m,n] * D_m[k-n]
//   D_m[x]   = sum_j E_j[x] * conj(E_j[x-m]),  D_{-m}[x] = conj(D_m[x+m])
//
// R15 was LDS-pipe-bound (~55% eff). This round: (a) D stored as packed
// bf16 pairs -> one 16B-aligned uint4 read = 4 complex taps (conv wave-
// instructions ~2.5x fewer; LDS footprint 61.6 -> 30.8 KB); (b) o0 = 4t
// (8 m-groups x 64 threads x 4 outputs) makes those reads aligned and
// lets consecutive-m groups CSE epilogue E reads. Pack via
// v_cvt_pk_bf16_f32 (1 instr); unpack = shl/and (2 VALU). bf16 D error
// ~0.003 absolute vs threshold 0.1775.

typedef float v2f __attribute__((ext_vector_type(2)));
typedef float v4f __attribute__((ext_vector_type(4)));

#define S_LEN 16384
#define SOUT  16284          // S - 2*L
#define BLK   512
#define NOUT  256            // outputs per block
#define NE    356            // staged E samples: [k0, k0+355]
#define NE2   178            // NE/2 (parity-split halves)
#define ND    307            // D tile: x in [k0+25, k0+331]
#define ND_AL 308            // row stride (rows fully written by pair loop)
#define NDP   154            // ND_AL/2 pairs per row

constexpr int LIMS[26] = {25,25,12,8,6,5,4,3,3,2,2,2,2,
                          1,1,1,1,1,1,1,1,1,1,1,1,1};
constexpr int TS[51] = {
      0,  3,  6,  9, 12, 15, 18, 21, 24, 27, 30, 33, 36,
     39, 44, 49, 54, 59, 66, 73, 82, 93,106,123,148,199,
    250,301,326,343,356,367,376,383,390,395,400,405,410,
    413,416,419,422,425,428,431,434,437,440,443,446};

__device__ __forceinline__ uint32_t pack_bf(float re, float im) {
    uint32_t r;
    asm("v_cvt_pk_bf16_f32 %0, %1, %2" : "=v"(r) : "v"(re), "v"(im));
    return r;                      // re -> [15:0], im -> [31:16]
}
__device__ __forceinline__ v2f unpack_bf(uint32_t u) {
    union { uint32_t i; float f; } lo, hi;
    lo.i = u << 16;
    hi.i = u & 0xFFFF0000u;
    return (v2f){lo.f, hi.f};
}

// One m (both signs), four outputs (o0..o0+3), bf16-packed D quads.
template<int M>
__device__ __forceinline__ void convM4(
    const uint32_t* __restrict__ sDm, const v4f* __restrict__ sEp,
    int o0, const float* __restrict__ Cr0, const float* __restrict__ Ci0,
    float4& acc01, float4& acc23)
{
    constexpr int lim = LIMS[M];
    constexpr int tp  = TS[25 + M];
    constexpr int tn  = TS[25 - M];
    constexpr int A   = 25 + lim;

    v2f SxP[4] = {{0.f,0.f},{0.f,0.f},{0.f,0.f},{0.f,0.f}};
    v2f SyP[4] = {{0.f,0.f},{0.f,0.f},{0.f,0.f},{0.f,0.f}};
    v2f SxN[4] = {{0.f,0.f},{0.f,0.f},{0.f,0.f},{0.f,0.f}};
    v2f SyN[4] = {{0.f,0.f},{0.f,0.f},{0.f,0.f},{0.f,0.f}};

    // element d (compile-time after unroll), data dd; P and N taps guarded
#define TAP4(d_, dd)                                                        \
    { _Pragma("unroll")                                                     \
      for (int r = 0; r < 4; ++r) {                                         \
        if (A + r - (d_) >= 0 && A + r - (d_) <= 2*lim) {                   \
            const float cx = Cr0[tp + A + r - (d_)];                        \
            const float cy = Ci0[tp + A + r - (d_)];                        \
            SxP[r] += cx * (dd);  SyP[r] += cy * (dd);                      \
        }                                                                   \
        if (A + M + r - (d_) >= 0 && A + M + r - (d_) <= 2*lim) {           \
            const float cx = Cr0[tn + A + M + r - (d_)];                    \
            const float cy = Ci0[tn + A + M + r - (d_)];                    \
            SxN[r] += cx * (dd);  SyN[r] += cy * (dd);                      \
        }                                                                   \
      } }
#define TAP4P(d_, dd)                                                       \
    { _Pragma("unroll")                                                     \
      for (int r = 0; r < 4; ++r) {                                         \
        if (A + r - (d_) >= 0 && A + r - (d_) <= 2*lim) {                   \
            const float cx = Cr0[tp + A + r - (d_)];                        \
            const float cy = Ci0[tp + A + r - (d_)];                        \
            SxP[r] += cx * (dd);  SyP[r] += cy * (dd);                      \
        }                                                                   \
      } }
#define TAP4N(d_, dd)                                                       \
    { _Pragma("unroll")                                                     \
      for (int r = 0; r < 4; ++r) {                                         \
        if (A + M + r - (d_) >= 0 && A + M + r - (d_) <= 2*lim) {           \
            const float cx = Cr0[tn + A + M + r - (d_)];                    \
            const float cy = Ci0[tn + A + M + r - (d_)];                    \
            SxN[r] += cx * (dd);  SyN[r] += cy * (dd);                      \
        }                                                                   \
      } }
#define QUAD(d0_, TAPM)                                                     \
    {                                                                       \
        uint4 u = *reinterpret_cast<const uint4*>(&sDm[o0 + (d0_)]);        \
        TAPM((d0_) + 0, unpack_bf(u.x))                                     \
        TAPM((d0_) + 1, unpack_bf(u.y))                                     \
        TAPM((d0_) + 2, unpack_bf(u.z))                                     \
        TAPM((d0_) + 3, unpack_bf(u.w))                                     \
    }

    if constexpr (M < 2*lim + 4) {
        // merged window: d in [25-lim, 28+lim+M]
        constexpr int dlo = (25 - lim) & ~3;
        constexpr int dhi = 28 + lim + M;
        constexpr int NQ  = (dhi - dlo) / 4 + 1;
        #pragma unroll
        for (int q = 0; q < NQ; ++q)
            QUAD(dlo + 4*q, TAP4)
    } else {
        // +m window: d in [25-lim, 28+lim]
        {
            constexpr int dlo = (25 - lim) & ~3;
            constexpr int dhi = 28 + lim;
            constexpr int NQ  = (dhi - dlo) / 4 + 1;
            #pragma unroll
            for (int q = 0; q < NQ; ++q)
                QUAD(dlo + 4*q, TAP4P)
        }
        // -m window: d in [25+M-lim, 28+M+lim]
        {
            constexpr int dlo = (25 + M - lim) & ~3;
            constexpr int dhi = 28 + M + lim;
            constexpr int NQ  = (dhi - dlo) / 4 + 1;
            #pragma unroll
            for (int q = 0; q < NQ; ++q)
                QUAD(dlo + 4*q, TAP4N)
        }
    }
#undef QUAD
#undef TAP4
#undef TAP4P
#undef TAP4N

    // sign combine + E epilogue (E reads CSE across consecutive-m groups)
    #pragma unroll
    for (int r = 0; r < 4; ++r) {
        const float spr = SxP[r].x - SyP[r].y, spi = SxP[r].y + SyP[r].x;
        const float snr = SxN[r].x + SyN[r].y, sni = SyN[r].x - SxN[r].y;
        const int sp = o0 + 50 + r - M;        // sample of E[s-M]
        const int sn = o0 + 50 + r + M;        // sample of E[s+M]
        v4f ep = sEp[(sp >> 1) + ((sp & 1) ? NE2 : 0)];
        v4f en = sEp[(sn >> 1) + ((sn & 1) ? NE2 : 0)];
        const float c0 = spr*ep.x - spi*ep.y + snr*en.x - sni*en.y;
        const float c1 = spr*ep.z - spi*ep.w + snr*en.z - sni*en.w;
        if      (r == 0) { acc01.x += c0; acc01.y += c1; }
        else if (r == 1) { acc01.z += c0; acc01.w += c1; }
        else if (r == 2) { acc23.x += c0; acc23.y += c1; }
        else             { acc23.z += c0; acc23.w += c1; }
    }
}

// m = 0: real D (f32 tile), out r: j = 50 + r - d, d in [0, 53].
__device__ __forceinline__ void conv04(
    const float* __restrict__ sD0p, const v4f* __restrict__ sEp,
    int o0, const float* __restrict__ Cr0, const float* __restrict__ Ci0,
    float4& acc01, float4& acc23)
{
    v2f s[4] = {{0.f,0.f},{0.f,0.f},{0.f,0.f},{0.f,0.f}};
    #pragma unroll
    for (int q = 0; q < 14; ++q) {
        const int d0 = 4*q;
        v4f w = *reinterpret_cast<const v4f*>(&sD0p[o0 + d0]);
        #pragma unroll
        for (int e = 0; e < 4; ++e) {
            const int d = d0 + e;
            const float dv = (e==0) ? w.x : (e==1) ? w.y : (e==2) ? w.z : w.w;
            #pragma unroll
            for (int r = 0; r < 4; ++r) {
                if (50 + r - d >= 0 && 50 + r - d <= 50) {
                    v2f cv = { Cr0[199 + 50 + r - d], Ci0[199 + 50 + r - d] };
                    s[r] += dv * cv;
                }
            }
        }
    }
    #pragma unroll
    for (int r = 0; r < 4; ++r) {
        const int sp = o0 + 50 + r;
        v4f e = sEp[(sp >> 1) + ((sp & 1) ? NE2 : 0)];
        const float c0 = s[r].x*e.x - s[r].y*e.y;
        const float c1 = s[r].x*e.z - s[r].y*e.w;
        if      (r == 0) { acc01.x += c0; acc01.y += c1; }
        else if (r == 1) { acc01.z += c0; acc01.w += c1; }
        else if (r == 2) { acc23.x += c0; acc23.y += c1; }
        else             { acc23.z += c0; acc23.w += c1; }
    }
}

__global__ __launch_bounds__(BLK, 4) void pbc_kernel(
    const float* __restrict__ Er, const float* __restrict__ Ei,
    const float* __restrict__ Cr, const float* __restrict__ Ci,
    float* __restrict__ out)
{
    __shared__ __align__(16) v4f      sEp[NE];           //  5.7 KB
    __shared__ __align__(16) uint32_t sDbf[25 * ND_AL];  // 30.8 KB bf16-packed
    __shared__ __align__(16) float    sD0[ND_AL];        //  1.2 KB (m=0, f32)
    __shared__ __align__(16) float4   sAcc[7][64][2];    // 14.3 KB partials
    // total 52.1 KB

    const int b   = blockIdx.y;
    const int k0  = blockIdx.x * NOUT;
    const int tid = threadIdx.x;

    // ---- stage E tile, parity-split ----
    const float* erb = Er + (size_t)b * (S_LEN * 2);
    const float* eib = Ei + (size_t)b * (S_LEN * 2);
    if (tid < NE2) {
        const int i  = tid;
        const int kg = k0 + 2 * i;
        v4f rr = {0.f,0.f,0.f,0.f}, ii = {0.f,0.f,0.f,0.f};
        if (kg < S_LEN) {
            rr = *reinterpret_cast<const v4f*>(erb + 2 * kg);
            ii = *reinterpret_cast<const v4f*>(eib + 2 * kg);
        }
        sEp[i]       = (v4f){rr.x, ii.x, rr.y, ii.y};   // sample kg (even)
        sEp[i + NE2] = (v4f){rr.z, ii.z, rr.w, ii.w};   // sample kg+1 (odd)
    }
    __syncthreads();

    // ---- D tiles, pair-at-a-time ----
    if (tid < NDP) {
        const int xp = tid;
        v4f a0 = sEp[xp + 12 + NE2];    // sample 2xp+25 (odd)
        v4f a1 = sEp[xp + 13];          // sample 2xp+26 (even)
        float d0 = a0.x*a0.x + a0.y*a0.y + a0.z*a0.z + a0.w*a0.w;
        float d1 = a1.x*a1.x + a1.y*a1.y + a1.z*a1.z + a1.w*a1.w;
        *reinterpret_cast<float2*>(&sD0[2 * xp]) = make_float2(d0, d1);
    }
    for (int idx = tid; idx < 25 * NDP; idx += BLK) {
        const int m1 = idx / NDP;              // 0..24 -> m = m1+1
        const int xp = idx - m1 * NDP;
        const int m  = m1 + 1;
        v4f a0 = sEp[xp + 12 + NE2];           // sample 2xp+25
        v4f a1 = sEp[xp + 13];                 // sample 2xp+26
        const int sb  = 2 * xp + 25 - m;
        const int ib0 = (sb >> 1) + (sb & 1) * NE2;
        const int sb1 = sb + 1;
        const int ib1 = (sb1 >> 1) + (sb1 & 1) * NE2;
        v4f b0 = sEp[ib0], b1 = sEp[ib1];
        float gr0 = a0.x*b0.x + a0.y*b0.y + a0.z*b0.z + a0.w*b0.w;
        float gi0 = a0.y*b0.x - a0.x*b0.y + a0.w*b0.z - a0.z*b0.w;
        float gr1 = a1.x*b1.x + a1.y*b1.y + a1.z*b1.z + a1.w*b1.w;
        float gi1 = a1.y*b1.x - a1.x*b1.y + a1.w*b1.z - a1.z*b1.w;
        *reinterpret_cast<uint2*>(&sDbf[m1 * ND_AL + 2 * xp]) =
            make_uint2(pack_bf(gr0, gi0), pack_bf(gr1, gi1));
    }
    __syncthreads();

    // ---- conv: 8 groups x 64 threads x 4 outputs (consecutive-m runs) ----
    const int g  = tid >> 6;            // one wave per group
    const int t  = tid & 63;
    const int o0 = 4 * t;

    float4 acc01 = make_float4(0.f,0.f,0.f,0.f);
    float4 acc23 = make_float4(0.f,0.f,0.f,0.f);
#define DM(mm) (sDbf + ((mm) - 1) * ND_AL)
    if (g == 0) {
        conv04(sD0, sEp, o0, Cr, Ci, acc01, acc23);
        convM4<1>(DM(1), sEp, o0, Cr, Ci, acc01, acc23);
    } else if (g == 1) {
        convM4<2>(DM(2), sEp, o0, Cr, Ci, acc01, acc23);
        convM4<3>(DM(3), sEp, o0, Cr, Ci, acc01, acc23);
        convM4<4>(DM(4), sEp, o0, Cr, Ci, acc01, acc23);
    } else if (g == 2) {
        convM4<5>(DM(5), sEp, o0, Cr, Ci, acc01, acc23);
        convM4<6>(DM(6), sEp, o0, Cr, Ci, acc01, acc23);
        convM4<7>(DM(7), sEp, o0, Cr, Ci, acc01, acc23);
    } else if (g == 3) {
        convM4<8>(DM(8), sEp, o0, Cr, Ci, acc01, acc23);
        convM4<9>(DM(9), sEp, o0, Cr, Ci, acc01, acc23);
        convM4<10>(DM(10), sEp, o0, Cr, Ci, acc01, acc23);
    } else if (g == 4) {
        convM4<11>(DM(11), sEp, o0, Cr, Ci, acc01, acc23);
        convM4<12>(DM(12), sEp, o0, Cr, Ci, acc01, acc23);
        convM4<13>(DM(13), sEp, o0, Cr, Ci, acc01, acc23);
        convM4<14>(DM(14), sEp, o0, Cr, Ci, acc01, acc23);
    } else if (g == 5) {
        convM4<15>(DM(15), sEp, o0, Cr, Ci, acc01, acc23);
        convM4<16>(DM(16), sEp, o0, Cr, Ci, acc01, acc23);
        convM4<17>(DM(17), sEp, o0, Cr, Ci, acc01, acc23);
        convM4<18>(DM(18), sEp, o0, Cr, Ci, acc01, acc23);
    } else if (g == 6) {
        convM4<19>(DM(19), sEp, o0, Cr, Ci, acc01, acc23);
        convM4<20>(DM(20), sEp, o0, Cr, Ci, acc01, acc23);
        convM4<21>(DM(21), sEp, o0, Cr, Ci, acc01, acc23);
        convM4<22>(DM(22), sEp, o0, Cr, Ci, acc01, acc23);
    } else {
        convM4<23>(DM(23), sEp, o0, Cr, Ci, acc01, acc23);
        convM4<24>(DM(24), sEp, o0, Cr, Ci, acc01, acc23);
        convM4<25>(DM(25), sEp, o0, Cr, Ci, acc01, acc23);
    }
#undef DM
    if (g > 0) {
        sAcc[g - 1][t][0] = acc01;
        sAcc[g - 1][t][1] = acc23;
    }
    __syncthreads();

    // ---- combine: wave 0 sums 7 partials + own acc, adds E, stores ----
    if (tid < 64) {
        const int tt = tid;
        const int oo = 4 * tt;
        const int ko = k0 + oo;
        if (ko < SOUT) {                  // SOUT % 4 == 0 -> full quad valid
            float4 a01 = acc01, a23 = acc23;
            #pragma unroll
            for (int i = 0; i < 7; ++i) {
                float4 p0 = sAcc[i][tt][0], p1 = sAcc[i][tt][1];
                a01.x += p0.x; a01.y += p0.y; a01.z += p0.z; a01.w += p0.w;
                a23.x += p1.x; a23.y += p1.y; a23.z += p1.z; a23.w += p1.w;
            }
            v4f e0 = sEp[2*tt + 25];          // sample oo+50 (even)
            v4f e1 = sEp[2*tt + 25 + NE2];    // sample oo+51 (odd)
            v4f e2 = sEp[2*tt + 26];          // sample oo+52 (even)
            v4f e3 = sEp[2*tt + 26 + NE2];    // sample oo+53 (odd)
            float4 o0v, o1v;
            o0v.x = e0.x + a01.x;  o0v.y = e0.z + a01.y;   // ko
            o0v.z = e1.x + a01.z;  o0v.w = e1.z + a01.w;   // ko+1
            o1v.x = e2.x + a23.x;  o1v.y = e2.z + a23.y;   // ko+2
            o1v.z = e3.x + a23.z;  o1v.w = e3.z + a23.w;   // ko+3
            float* dst = out + ((size_t)b * SOUT + ko) * 2;
            *reinterpret_cast<float4*>(dst)     = o0v;
            *reinterpret_cast<float4*>(dst + 4) = o1v;
        }
    }
}

extern "C" void kernel_launch(void* const* d_in, const int* in_sizes, int n_in,
                              void* d_out, int out_size, void* d_ws, size_t ws_size,
                              hipStream_t stream) {
    const float* Er = (const float*)d_in[0];
    const float* Ei = (const float*)d_in[1];
    const float* Cr = (const float*)d_in[2];   // [4, 449], row 0 used
    const float* Ci = (const float*)d_in[3];
    float* out = (float*)d_out;                // [8, 16284, 2] float32 (Re)

    dim3 grid((SOUT + NOUT - 1) / NOUT, 8);
    pbc_kernel<<<grid, BLK, 0, stream>>>(Er, Ei, Cr, Ci, out);
}